// Round 8
// baseline (634.732 us; speedup 1.0000x reference)
//
#include <hip/hip_runtime.h>
#include <hip/hip_fp16.h>

// ---------------------------------------------------------------------------
// GCN: 4 layers of  h' = A_hat_norm (h @ W) + b   on fixed graph, fp32.
// deg[i] = in_degree(i) + 1 (self loop), dinv = 1/sqrt(deg),
// g = (h@W) * dinv[row]  (GEMM epilogue), then per-dst:
//   h'[dst] = dinv[dst] * ( g[dst] + sum_{src in N(dst)} g[src] ) + b
// R3/R4: binned counting-sort CSR build. (784us)
// R9/R10: gather MLP depth. fp32 agg was miss-path BW-bound. (748us)
// R11: fp16 G. FETCH 161MB, agg 71us. (587us)
// R12: 32 rows in flight, byte-offset col. (579us, agg 69.8us)
// R13: coop mega-fusion 1358us CATASTROPHE (grid.sync sleep-spin).
// R14: LDS-staged tile GEMM: 555us. GEMM ~60us each vs ~16 model.
// R15: grid-stride A/B: agg 69->90 REGRESSED (persistent blocks disperse
//   the gather window; exact-grid fine blocks win). gemm grid-stride kept.
// R16: fused agg+W-mult for layers 1-3 (Y round-trip deleted): 609us.
//   agg_gemm=107 vs agg=69. Root cause found in counters:
//   SQ_LDS_BANK_CONFLICT = 6.4M = 100k waves x 16 W-reads x 4 extra cyc.
//   The f8 lane-stride is 8 rows = 8*68 = 544 floats == 0 mod 32 -> all
//   8 f8-groups hit one bank quad: 16-way conflict per ds_read_b128.
// R17: conflict-free W layout: WAs/WBs indexed by (rr, lane) so the read
//   at step rr is WAs[rr*64+lane] -- 64 lanes x 16B CONTIGUOUS. Same
//   values, same fma order as R16 (numerics identical). LDS 16KB.
//   Predict: conflicts ->~0, agg_gemm 107->~88, wall 609->~545.
// ---------------------------------------------------------------------------

#define FEAT 128
#define EMB 64
#define BINSHIFT 8
#define BINSIZE 256
#define NBIN 391          // ceil(100000/256)
#define CHUNK 8192

// ---------------- CSR build (unchanged, proven) ----------------

__global__ __launch_bounds__(256) void bin_count_k(
    const int* __restrict__ dst, int* __restrict__ bincnt, int E) {
    __shared__ int hist[NBIN];
    int t = threadIdx.x;
    int base = blockIdx.x * CHUNK;
    int end = min(base + CHUNK, E);
    for (int i = t; i < NBIN; i += 256) hist[i] = 0;
    __syncthreads();
    for (int e = base + t; e < end; e += 256)
        atomicAdd(&hist[dst[e] >> BINSHIFT], 1);
    __syncthreads();
    for (int b = t; b < NBIN; b += 256) {
        int c = hist[b];
        if (c > 0) atomicAdd(&bincnt[b], c);
    }
}

__global__ void binscan_k(const int* __restrict__ bincnt, int* __restrict__ binptr,
                          int* __restrict__ bincur, int nbin, int E) {
    __shared__ int s[512];
    int t = threadIdx.x;
    int v = (t < nbin) ? bincnt[t] : 0;
    s[t] = v;
    __syncthreads();
    for (int off = 1; off < 512; off <<= 1) {
        int tv = (t >= off) ? s[t - off] : 0;
        __syncthreads();
        s[t] += tv;
        __syncthreads();
    }
    if (t < nbin) {
        int excl = s[t] - v;
        binptr[t] = excl;
        bincur[t] = excl;
    }
    if (t == 0) binptr[nbin] = E;
}

__global__ __launch_bounds__(256) void bin_edges_k(
    const int* __restrict__ src, const int* __restrict__ dst,
    int* __restrict__ bincur, int* __restrict__ ebuf, int E) {
    __shared__ int hist[NBIN];
    __shared__ int lcur[NBIN];
    int t = threadIdx.x;
    int base = blockIdx.x * CHUNK;
    int end = min(base + CHUNK, E);
    for (int i = t; i < NBIN; i += 256) hist[i] = 0;
    __syncthreads();
    for (int e = base + t; e < end; e += 256)
        atomicAdd(&hist[dst[e] >> BINSHIFT], 1);
    __syncthreads();
    for (int b = t; b < NBIN; b += 256) {
        int c = hist[b];
        lcur[b] = (c > 0) ? atomicAdd(&bincur[b], c) : 0;
    }
    __syncthreads();
    for (int e = base + t; e < end; e += 256) {
        int d = dst[e];
        int bin = d >> BINSHIFT;
        int r = atomicAdd(&lcur[bin], 1);
        ebuf[r] = src[e] | ((d & (BINSIZE - 1)) << 24);
    }
}

__global__ __launch_bounds__(256) void build_csr_k(
    const int* __restrict__ ebuf, const int* __restrict__ binptr,
    int* __restrict__ rowptr, float* __restrict__ dinv,
    int* __restrict__ col, int N, int E, int nbin) {
    __shared__ int lcnt[BINSIZE];
    __shared__ int lscan[BINSIZE];
    __shared__ int lcur[BINSIZE];
    int b = blockIdx.x;
    int t = threadIdx.x;
    int n0 = b << BINSHIFT;
    int e0 = binptr[b];
    int e1 = binptr[b + 1];

    lcnt[t] = 0;
    __syncthreads();
    for (int i = e0 + t; i < e1; i += 256)
        atomicAdd(&lcnt[((unsigned)ebuf[i]) >> 24], 1);
    __syncthreads();

    int v = lcnt[t];
    lscan[t] = v;
    __syncthreads();
    for (int off = 1; off < 256; off <<= 1) {
        int tv = (t >= off) ? lscan[t - off] : 0;
        __syncthreads();
        lscan[t] += tv;
        __syncthreads();
    }
    int excl = e0 + lscan[t] - v;
    lcur[t] = excl;
    if (n0 + t < N) {
        rowptr[n0 + t] = excl;
        dinv[n0 + t] = 1.0f / sqrtf((float)(v + 1));
    }
    if (b == nbin - 1 && t == 0) rowptr[N] = E;
    __syncthreads();

    for (int i = e0 + t; i < e1; i += 256) {
        int w = ebuf[i];
        int dl = ((unsigned)w) >> 24;
        int p = atomicAdd(&lcur[dl], 1);
        col[p] = (w & 0xFFFFFF) << 7;   // byte offset into fp16 G (row = 128B)
    }
}

// ---------------- GEMM (layer 0 only): G = (x @ W0) * dinv[row], fp16 out ----
// R15 form: tile-stride over 64-row tiles, W staged once per block,
// A-tile staged per tile (BK=64 chunks, stride-68 pad).

#define AKP 68   // padded A-tile row stride in floats (BK=64 + 4)

template <int K>
__global__ __launch_bounds__(256, 4) void gemm_scale_k(
    const float* __restrict__ H, const float* __restrict__ W,
    const float* __restrict__ dinv, __half* __restrict__ G, int N, int ntile) {
    __shared__ float Ws[K * EMB];        // B: K x 64
    __shared__ float As[64 * AKP];       // A chunk: 64 x 64 (+4 pad)
    int t = threadIdx.x;

    for (int i = t * 4; i < K * EMB; i += 1024)
        *(float4*)(Ws + i) = *(const float4*)(W + i);

    int tc = t & 15;   // col group -> 4 cols
    int tr = t >> 4;   // row group -> 4 rows
    int j0 = tc * 4;

    for (int tile = blockIdx.x; tile < ntile; tile += gridDim.x) {
        int r0blk = tile * 64;
        float acc[4][4] = {{0.f}};

        for (int k0 = 0; k0 < K; k0 += 64) {
            __syncthreads();   // prev readers (and Ws stage on 1st pass) done
#pragma unroll
            for (int n = 0; n < 4; n++) {
                int idx = t + n * 256;
                int row = idx >> 4;          // 16 float4 per row
                int cg  = idx & 15;
                int r = r0blk + row;
                if (r >= N) r = N - 1;       // clamp (harmless dup read)
                *(float4*)(As + row * AKP + cg * 4) =
                    *(const float4*)(H + (size_t)r * K + k0 + cg * 4);
            }
            __syncthreads();

#pragma unroll 2
            for (int k = 0; k < 64; k += 4) {
                float4 a[4];
#pragma unroll
                for (int i = 0; i < 4; i++)
                    a[i] = *(const float4*)(As + (tr * 4 + i) * AKP + k);
#pragma unroll
                for (int kk = 0; kk < 4; kk++) {
                    float4 wv = *(const float4*)(Ws + (k0 + k + kk) * EMB + j0);
#pragma unroll
                    for (int i = 0; i < 4; i++) {
                        float av = (kk == 0) ? a[i].x : (kk == 1) ? a[i].y
                                 : (kk == 2) ? a[i].z : a[i].w;
                        acc[i][0] = fmaf(av, wv.x, acc[i][0]);
                        acc[i][1] = fmaf(av, wv.y, acc[i][1]);
                        acc[i][2] = fmaf(av, wv.z, acc[i][2]);
                        acc[i][3] = fmaf(av, wv.w, acc[i][3]);
                    }
                }
            }
        }

        int r0 = r0blk + tr * 4;
#pragma unroll
        for (int i = 0; i < 4; i++) {
            if (r0 + i < N) {
                float s = dinv[r0 + i];
                union { __half2 h2[2]; float2 f2; } o;
                o.h2[0] = __floats2half2_rn(acc[i][0] * s, acc[i][1] * s);
                o.h2[1] = __floats2half2_rn(acc[i][2] * s, acc[i][3] * s);
                *(float2*)(G + (size_t)(r0 + i) * EMB + j0) = o.f2;
            }
        }
    }
}

// ---------------- Aggregation core (R12, proven) ----------------
// 8 lanes per 128B fp16 row (dwordx4); 8 groups/wave -> one load instr =
// 8 rows; 4 chains -> 32 rows outstanding. fp32 accumulate; epilogue
// shfl_xor(8,16,32) leaves the FULL h-row in every lane (8 feats each).

__device__ __forceinline__ void h8_acc(float (&a)[8], float4 raw) {
    union { float4 f4; __half2 h2[4]; } u;
    u.f4 = raw;
    float2 p0 = __half22float2(u.h2[0]);
    float2 p1 = __half22float2(u.h2[1]);
    float2 p2 = __half22float2(u.h2[2]);
    float2 p3 = __half22float2(u.h2[3]);
    a[0] += p0.x; a[1] += p0.y; a[2] += p1.x; a[3] += p1.y;
    a[4] += p2.x; a[5] += p2.y; a[6] += p3.x; a[7] += p3.y;
}

__device__ __forceinline__ void agg_node8(const __half* __restrict__ G,
                                          const int* __restrict__ coff,
                                          int s, int e, int selfoff,
                                          int grp, int f8, float (&r)[8]) {
    const char* Gb = (const char*)G + f8 * 16;   // lane's 16B slice in a row
    float a0[8] = {0.f, 0.f, 0.f, 0.f, 0.f, 0.f, 0.f, 0.f};
    float a1[8] = {0.f, 0.f, 0.f, 0.f, 0.f, 0.f, 0.f, 0.f};
    float a2[8] = {0.f, 0.f, 0.f, 0.f, 0.f, 0.f, 0.f, 0.f};
    float a3[8] = {0.f, 0.f, 0.f, 0.f, 0.f, 0.f, 0.f, 0.f};
    if (grp == 0) h8_acc(a0, *(const float4*)(Gb + selfoff));  // self loop

    int i = s;
    if (i + 32 <= e) {
        int c0 = coff[i + grp];
        int c1 = coff[i + 8 + grp];
        int c2 = coff[i + 16 + grp];
        int c3 = coff[i + 24 + grp];
        while (true) {
            float4 g0 = *(const float4*)(Gb + (size_t)(unsigned)c0);
            float4 g1 = *(const float4*)(Gb + (size_t)(unsigned)c1);
            float4 g2 = *(const float4*)(Gb + (size_t)(unsigned)c2);
            float4 g3 = *(const float4*)(Gb + (size_t)(unsigned)c3);
            i += 32;
            bool more = (i + 32 <= e);
            if (more) {                       // prefetch next iter's offsets
                c0 = coff[i + grp];
                c1 = coff[i + 8 + grp];
                c2 = coff[i + 16 + grp];
                c3 = coff[i + 24 + grp];
            }
            h8_acc(a0, g0);
            h8_acc(a1, g1);
            h8_acc(a2, g2);
            h8_acc(a3, g3);
            if (!more) break;
        }
    }
    for (; i + 8 <= e; i += 8) {
        float4 g = *(const float4*)(Gb + (size_t)(unsigned)coff[i + grp]);
        h8_acc(a1, g);
    }
    if (grp < e - i) {
        float4 g = *(const float4*)(Gb + (size_t)(unsigned)coff[i + grp]);
        h8_acc(a2, g);
    }

#pragma unroll
    for (int k = 0; k < 8; k++) {
        float v = (a0[k] + a1[k]) + (a2[k] + a3[k]);
        v += __shfl_xor(v, 8, 64);
        v += __shfl_xor(v, 16, 64);
        v += __shfl_xor(v, 32, 64);
        r[k] = v;   // all 64 lanes: full sum for features [8*f8 .. 8*f8+7]
    }
}

// ---------------- Fused agg + next-layer GEMM (layers 1..3) ----------------
// h'[gw] = dinv*Sum + b (fp32, in registers); then G_next = (h'@Wn)*dinv
// as fp16. Lane (g=grp, j=f8) computes outputs 8g..8g+7 over input slice
// 8j..8j+7, xor-reduce over j; j==0 lanes store 16B each (128B row).
// R17: W staged in READ-ORDER layout: WAs[rr*64+lane], WBs[rr*64+lane]
// hold W[8*(lane&7)+rr][8*(lane>>3)+{0..3,4..7}] -> every ds_read_b128 is
// 64 lanes x 16B contiguous = conflict-free (R16's row-major+pad layout
// had f8-stride 544 floats == 0 mod 32 -> 16-way conflicts, 6.4M/dispatch).

__global__ __launch_bounds__(256) void agg_gemm_k(
    const __half* __restrict__ G, const float* __restrict__ dinv,
    const int* __restrict__ rowptr, const int* __restrict__ coff,
    const float* __restrict__ bias, const float* __restrict__ Wn,
    __half* __restrict__ Gout, int N) {
    __shared__ float4 WAs[512];   // [rr][lane] : W[8*f8+rr][8*grp + 0..3]
    __shared__ float4 WBs[512];   // [rr][lane] : W[8*f8+rr][8*grp + 4..7]
    int t = threadIdx.x;
    for (int i = t; i < 512; i += 256) {
        int rr = i >> 6;
        int ln = i & 63;
        const float* src = Wn + ((ln & 7) * 8 + rr) * EMB + (ln >> 3) * 8;
        WAs[i] = *(const float4*)(src);
        WBs[i] = *(const float4*)(src + 4);
    }
    __syncthreads();

    int gw = (blockIdx.x * 256 + t) >> 6;
    int lane = t & 63;
    if (gw >= N) return;
    gw = __builtin_amdgcn_readfirstlane(gw);    // wave-uniform -> scalar loads
    int grp = lane >> 3;   // g: output block
    int f8 = lane & 7;     // j: input slice
    int s = rowptr[gw], e = rowptr[gw + 1];
    float r[8];
    agg_node8(G, coff, s, e, gw << 7, grp, f8, r);
    float d = dinv[gw];
    float4 b0v = *(const float4*)(bias + f8 * 8);
    float4 b1v = *(const float4*)(bias + f8 * 8 + 4);
    float h[8];
    h[0] = r[0] * d + b0v.x; h[1] = r[1] * d + b0v.y;
    h[2] = r[2] * d + b0v.z; h[3] = r[3] * d + b0v.w;
    h[4] = r[4] * d + b1v.x; h[5] = r[5] * d + b1v.y;
    h[6] = r[6] * d + b1v.z; h[7] = r[7] * d + b1v.w;

    // p[o'] = sum_rr h[rr] * Wn[8*f8+rr][8*grp+o']
    float p[8] = {0.f, 0.f, 0.f, 0.f, 0.f, 0.f, 0.f, 0.f};
#pragma unroll
    for (int rr = 0; rr < 8; rr++) {
        float4 wa = WAs[rr * 64 + lane];    // contiguous across lanes
        float4 wb = WBs[rr * 64 + lane];
        float hv = h[rr];
        p[0] = fmaf(hv, wa.x, p[0]); p[1] = fmaf(hv, wa.y, p[1]);
        p[2] = fmaf(hv, wa.z, p[2]); p[3] = fmaf(hv, wa.w, p[3]);
        p[4] = fmaf(hv, wb.x, p[4]); p[5] = fmaf(hv, wb.y, p[5]);
        p[6] = fmaf(hv, wb.z, p[6]); p[7] = fmaf(hv, wb.w, p[7]);
    }
    // reduce over the 8 input slices (lane bits 0..2)
#pragma unroll
    for (int k = 0; k < 8; k++) {
        p[k] += __shfl_xor(p[k], 1, 64);
        p[k] += __shfl_xor(p[k], 2, 64);
        p[k] += __shfl_xor(p[k], 4, 64);
    }
    if (f8 == 0) {
        union { __half2 h2[4]; float4 f4; } o;
        o.h2[0] = __floats2half2_rn(p[0] * d, p[1] * d);
        o.h2[1] = __floats2half2_rn(p[2] * d, p[3] * d);
        o.h2[2] = __floats2half2_rn(p[4] * d, p[5] * d);
        o.h2[3] = __floats2half2_rn(p[6] * d, p[7] * d);
        *(float4*)((char*)Gout + ((size_t)gw << 7) + grp * 16) = o.f4;
    }
}

// ---------------- Final layer: agg + y store + output projection ----------------

__global__ __launch_bounds__(256) void agg_final_k(
    const __half* __restrict__ G, const float* __restrict__ dinv,
    const int* __restrict__ rowptr, const int* __restrict__ coff,
    const float* __restrict__ bias, const float* __restrict__ Wout,
    const float* __restrict__ bout, float* __restrict__ Y,
    float* __restrict__ Out, int N) {
    int gw = (blockIdx.x * 256 + threadIdx.x) >> 6;
    int lane = threadIdx.x & 63;
    if (gw >= N) return;
    gw = __builtin_amdgcn_readfirstlane(gw);
    int grp = lane >> 3;
    int f8 = lane & 7;
    int s = rowptr[gw], e = rowptr[gw + 1];
    float r[8];
    agg_node8(G, coff, s, e, gw << 7, grp, f8, r);
    float d = dinv[gw];
    float4 b0v = *(const float4*)(bias + f8 * 8);
    float4 b1v = *(const float4*)(bias + f8 * 8 + 4);
    float v0 = r[0] * d + b0v.x, v1 = r[1] * d + b0v.y;
    float v2 = r[2] * d + b0v.z, v3 = r[3] * d + b0v.w;
    float v4 = r[4] * d + b1v.x, v5 = r[5] * d + b1v.y;
    float v6 = r[6] * d + b1v.z, v7 = r[7] * d + b1v.w;
    if (grp == 0) {
        float* o = Y + (size_t)gw * EMB + f8 * 8;
        *(float4*)o = make_float4(v0, v1, v2, v3);
        *(float4*)(o + 4) = make_float4(v4, v5, v6, v7);
    }
    // output projection: lanes 0..7 cover all 64 features.
    float4 w0v = *(const float4*)(Wout + f8 * 8);
    float4 w1v = *(const float4*)(Wout + f8 * 8 + 4);
    float p = v0 * w0v.x + v1 * w0v.y + v2 * w0v.z + v3 * w0v.w +
              v4 * w1v.x + v5 * w1v.y + v6 * w1v.z + v7 * w1v.w;
    p += __shfl_xor(p, 1, 8);
    p += __shfl_xor(p, 2, 8);
    p += __shfl_xor(p, 4, 8);
    if (lane == 0) Out[gw] = p + bout[0];
}

// ---------------- launch ----------------

extern "C" void kernel_launch(void* const* d_in, const int* in_sizes, int n_in,
                              void* d_out, int out_size, void* d_ws, size_t ws_size,
                              hipStream_t stream) {
    const float* x    = (const float*)d_in[0];
    const int*   ei   = (const int*)d_in[1];
    const float* W0   = (const float*)d_in[3];
    const float* b0   = (const float*)d_in[4];
    const float* W1   = (const float*)d_in[5];
    const float* b1   = (const float*)d_in[6];
    const float* W2   = (const float*)d_in[7];
    const float* b2   = (const float*)d_in[8];
    const float* W3   = (const float*)d_in[9];
    const float* b3   = (const float*)d_in[10];
    const float* Wout = (const float*)d_in[11];
    const float* bout = (const float*)d_in[12];

    const int N = in_sizes[0] / FEAT;      // 100000
    const int E = in_sizes[1] / 2;         // 3200000
    const int* srcp = ei;                  // edge_index[0]
    const int* dstp = ei + E;              // edge_index[1]
    const int nbin = (N + BINSIZE - 1) / BINSIZE;   // 391

    // workspace layout (regions padded to 64 elems for float4 alignment)
    const int NP = ((N + 64) + 63) / 64 * 64;   // holds N+1
    float* dinv  = (float*)d_ws;
    int* rowptr  = (int*)(dinv + NP);
    int* bincnt  = rowptr + NP;
    int* binptr  = bincnt + 1024;
    int* bincur  = binptr + 1024;
    int* col     = bincur + 1024;
    float* bufA  = (float*)(col + ((E + 63) / 64) * 64);
    int* ebuf    = (int*)bufA;             // aliased: ebuf dead before gemm0
    __half* Gbuf0 = (__half*)bufA;         // fp16 G ping (12.8MB)
    __half* Gbuf1 = Gbuf0 + (size_t)N * EMB;  // fp16 G pong (12.8MB)

    float* Out = (float*)d_out;
    float* Y   = Out + N;                  // y-region of d_out (final only)

    const int ntile = (N + 63) / 64;               // 1563
    const int gemm_grid = (ntile < 768) ? ntile : 768;
    const int agg_blocks = (N + 3) / 4;            // 25000 (exact-grid: R15
                                                   // proved fine blocks win)
    const int nchunk = (E + CHUNK - 1) / CHUNK;

    // --- CSR build ---
    hipMemsetAsync(bincnt, 0, 1024 * sizeof(int), stream);
    bin_count_k<<<nchunk, 256, 0, stream>>>(dstp, bincnt, E);
    binscan_k<<<1, 512, 0, stream>>>(bincnt, binptr, bincur, nbin, E);
    bin_edges_k<<<nchunk, 256, 0, stream>>>(srcp, dstp, bincur, ebuf, E);
    build_csr_k<<<nbin, 256, 0, stream>>>(ebuf, binptr, rowptr, dinv, col, N, E, nbin);

    // --- layer 0 GEMM (K=128): G0 = (x@W0)*dinv ---
    gemm_scale_k<FEAT><<<gemm_grid, 256, 0, stream>>>(x, W0, dinv, Gbuf0, N, ntile);
    // --- layers 1-3 fused: gather G_prev -> h' -> (h'@W_next)*dinv -> G_next ---
    agg_gemm_k<<<agg_blocks, 256, 0, stream>>>(Gbuf0, dinv, rowptr, col, b0, W1, Gbuf1, N);
    agg_gemm_k<<<agg_blocks, 256, 0, stream>>>(Gbuf1, dinv, rowptr, col, b1, W2, Gbuf0, N);
    agg_gemm_k<<<agg_blocks, 256, 0, stream>>>(Gbuf0, dinv, rowptr, col, b2, W3, Gbuf1, N);
    // --- final: gather G3 -> y (fp32) + projection ---
    agg_final_k<<<agg_blocks, 256, 0, stream>>>(Gbuf1, dinv, rowptr, col, b3, Wout, bout,
                                                Y, Out, N);
}

// Round 9
// 579.234 us; speedup vs baseline: 1.0958x; 1.0958x over previous
//
#include <hip/hip_runtime.h>
#include <hip/hip_fp16.h>

// ---------------------------------------------------------------------------
// GCN: 4 layers of  h' = A_hat_norm (h @ W) + b   on fixed graph, fp32.
// deg[i] = in_degree(i) + 1 (self loop), dinv = 1/sqrt(deg),
// g = (h@W) * dinv[row]  (GEMM epilogue), then per-dst:
//   h'[dst] = dinv[dst] * ( g[dst] + sum_{src in N(dst)} g[src] ) + b
// R3/R4: binned counting-sort CSR. R9-R12: gather widened to 32 rows in
//   flight, fp16 G, byte-offset col. agg = 69us, pinned at L2-fill
//   transaction rate (1 fill/cyc/XCD; G is L3-resident, FETCH = L2 fills).
// R13: coop mega-fusion 1358us CATASTROPHE (grid.sync sleep-spin).
// R14: LDS-staged tile GEMM, split structure: 555us == BEST.
// R15: grid-stride A/B: agg 69->90 REGRESSED (persistent blocks disperse
//   the gather window -> exact-grid fine blocks win); gemm grid-stride
//   helped ~5us each (kept).
// R16: fused agg+W epilogue: 609us. 6.4M LDS bank conflicts found.
// R17: conflict-free W layout: conflicts -> 0 EXACTLY as predicted, time
//   UNCHANGED (112 vs 107) -> conflicts were hidden under other stalls;
//   epilogue's real cost is ~21us unhidden VALU + staging barriers.
//   Fused walls also carry ~130us unreconciled vs ~12 for split. ABANDON
//   fusion; empirical ranking: split-555 < fused-609/635.
// R18: recombination + fp16 handoff:
//   (a) R14 split structure, exact-grid aggs (proven 69us bodies);
//   (b) R15 grid-stride gemms (proven -5us each);
//   (c) NEW: inner h handoffs stored fp16 (Yh buffer): agg WRITE 26->13MB,
//       inner gemm reads 25.6->12.8MB. One extra rounding per layer
//       (fp16-G was invisible; predict absmax ~3e-4..1e-3, still passing).
//   Predict: aggs ~66-70 (FETCH ~161MB, WRITE ~13MB), wall 555 -> ~505-530.
//   Fork: absmax fail => revert (c) only, land ~535.
// ---------------------------------------------------------------------------

#define FEAT 128
#define EMB 64
#define BINSHIFT 8
#define BINSIZE 256
#define NBIN 391          // ceil(100000/256)
#define CHUNK 8192

// ---------------- CSR build (unchanged, proven) ----------------

__global__ __launch_bounds__(256) void bin_count_k(
    const int* __restrict__ dst, int* __restrict__ bincnt, int E) {
    __shared__ int hist[NBIN];
    int t = threadIdx.x;
    int base = blockIdx.x * CHUNK;
    int end = min(base + CHUNK, E);
    for (int i = t; i < NBIN; i += 256) hist[i] = 0;
    __syncthreads();
    for (int e = base + t; e < end; e += 256)
        atomicAdd(&hist[dst[e] >> BINSHIFT], 1);
    __syncthreads();
    for (int b = t; b < NBIN; b += 256) {
        int c = hist[b];
        if (c > 0) atomicAdd(&bincnt[b], c);
    }
}

__global__ void binscan_k(const int* __restrict__ bincnt, int* __restrict__ binptr,
                          int* __restrict__ bincur, int nbin, int E) {
    __shared__ int s[512];
    int t = threadIdx.x;
    int v = (t < nbin) ? bincnt[t] : 0;
    s[t] = v;
    __syncthreads();
    for (int off = 1; off < 512; off <<= 1) {
        int tv = (t >= off) ? s[t - off] : 0;
        __syncthreads();
        s[t] += tv;
        __syncthreads();
    }
    if (t < nbin) {
        int excl = s[t] - v;
        binptr[t] = excl;
        bincur[t] = excl;
    }
    if (t == 0) binptr[nbin] = E;
}

__global__ __launch_bounds__(256) void bin_edges_k(
    const int* __restrict__ src, const int* __restrict__ dst,
    int* __restrict__ bincur, int* __restrict__ ebuf, int E) {
    __shared__ int hist[NBIN];
    __shared__ int lcur[NBIN];
    int t = threadIdx.x;
    int base = blockIdx.x * CHUNK;
    int end = min(base + CHUNK, E);
    for (int i = t; i < NBIN; i += 256) hist[i] = 0;
    __syncthreads();
    for (int e = base + t; e < end; e += 256)
        atomicAdd(&hist[dst[e] >> BINSHIFT], 1);
    __syncthreads();
    for (int b = t; b < NBIN; b += 256) {
        int c = hist[b];
        lcur[b] = (c > 0) ? atomicAdd(&bincur[b], c) : 0;
    }
    __syncthreads();
    for (int e = base + t; e < end; e += 256) {
        int d = dst[e];
        int bin = d >> BINSHIFT;
        int r = atomicAdd(&lcur[bin], 1);
        ebuf[r] = src[e] | ((d & (BINSIZE - 1)) << 24);
    }
}

__global__ __launch_bounds__(256) void build_csr_k(
    const int* __restrict__ ebuf, const int* __restrict__ binptr,
    int* __restrict__ rowptr, float* __restrict__ dinv,
    int* __restrict__ col, int N, int E, int nbin) {
    __shared__ int lcnt[BINSIZE];
    __shared__ int lscan[BINSIZE];
    __shared__ int lcur[BINSIZE];
    int b = blockIdx.x;
    int t = threadIdx.x;
    int n0 = b << BINSHIFT;
    int e0 = binptr[b];
    int e1 = binptr[b + 1];

    lcnt[t] = 0;
    __syncthreads();
    for (int i = e0 + t; i < e1; i += 256)
        atomicAdd(&lcnt[((unsigned)ebuf[i]) >> 24], 1);
    __syncthreads();

    int v = lcnt[t];
    lscan[t] = v;
    __syncthreads();
    for (int off = 1; off < 256; off <<= 1) {
        int tv = (t >= off) ? lscan[t - off] : 0;
        __syncthreads();
        lscan[t] += tv;
        __syncthreads();
    }
    int excl = e0 + lscan[t] - v;
    lcur[t] = excl;
    if (n0 + t < N) {
        rowptr[n0 + t] = excl;
        dinv[n0 + t] = 1.0f / sqrtf((float)(v + 1));
    }
    if (b == nbin - 1 && t == 0) rowptr[N] = E;
    __syncthreads();

    for (int i = e0 + t; i < e1; i += 256) {
        int w = ebuf[i];
        int dl = ((unsigned)w) >> 24;
        int p = atomicAdd(&lcur[dl], 1);
        col[p] = (w & 0xFFFFFF) << 7;   // byte offset into fp16 G (row = 128B)
    }
}

// ---------------- GEMM 0 (fp32 input x, K=128): G = (x@W0)*dinv, fp16 out ----
// R15 form: tile-stride over 64-row tiles, W staged once per block,
// A-tile staged per tile (BK=64 chunks, stride-68 pad).

#define AKP 68   // padded A-tile row stride in floats (BK=64 + 4)

template <int K>
__global__ __launch_bounds__(256, 4) void gemm_scale_k(
    const float* __restrict__ H, const float* __restrict__ W,
    const float* __restrict__ dinv, __half* __restrict__ G, int N, int ntile) {
    __shared__ float Ws[K * EMB];        // B: K x 64
    __shared__ float As[64 * AKP];       // A chunk: 64 x 64 (+4 pad)
    int t = threadIdx.x;

    for (int i = t * 4; i < K * EMB; i += 1024)
        *(float4*)(Ws + i) = *(const float4*)(W + i);

    int tc = t & 15;   // col group -> 4 cols
    int tr = t >> 4;   // row group -> 4 rows
    int j0 = tc * 4;

    for (int tile = blockIdx.x; tile < ntile; tile += gridDim.x) {
        int r0blk = tile * 64;
        float acc[4][4] = {{0.f}};

        for (int k0 = 0; k0 < K; k0 += 64) {
            __syncthreads();   // prev readers (and Ws stage on 1st pass) done
#pragma unroll
            for (int n = 0; n < 4; n++) {
                int idx = t + n * 256;
                int row = idx >> 4;          // 16 float4 per row
                int cg  = idx & 15;
                int r = r0blk + row;
                if (r >= N) r = N - 1;       // clamp (harmless dup read)
                *(float4*)(As + row * AKP + cg * 4) =
                    *(const float4*)(H + (size_t)r * K + k0 + cg * 4);
            }
            __syncthreads();

#pragma unroll 2
            for (int k = 0; k < 64; k += 4) {
                float4 a[4];
#pragma unroll
                for (int i = 0; i < 4; i++)
                    a[i] = *(const float4*)(As + (tr * 4 + i) * AKP + k);
#pragma unroll
                for (int kk = 0; kk < 4; kk++) {
                    float4 wv = *(const float4*)(Ws + (k0 + k + kk) * EMB + j0);
#pragma unroll
                    for (int i = 0; i < 4; i++) {
                        float av = (kk == 0) ? a[i].x : (kk == 1) ? a[i].y
                                 : (kk == 2) ? a[i].z : a[i].w;
                        acc[i][0] = fmaf(av, wv.x, acc[i][0]);
                        acc[i][1] = fmaf(av, wv.y, acc[i][1]);
                        acc[i][2] = fmaf(av, wv.z, acc[i][2]);
                        acc[i][3] = fmaf(av, wv.w, acc[i][3]);
                    }
                }
            }
        }

        int r0 = r0blk + tr * 4;
#pragma unroll
        for (int i = 0; i < 4; i++) {
            if (r0 + i < N) {
                float s = dinv[r0 + i];
                union { __half2 h2[2]; float2 f2; } o;
                o.h2[0] = __floats2half2_rn(acc[i][0] * s, acc[i][1] * s);
                o.h2[1] = __floats2half2_rn(acc[i][2] * s, acc[i][3] * s);
                *(float2*)(G + (size_t)(r0 + i) * EMB + j0) = o.f2;
            }
        }
    }
}

// ---------------- Inner GEMM (fp16 input Yh, K=64): G = (Yh@W)*dinv, fp16 out ----
// Same structure; staging converts half8 -> 8 floats into As.

__global__ __launch_bounds__(256, 4) void gemm_scale_h_k(
    const __half* __restrict__ Hh, const float* __restrict__ W,
    const float* __restrict__ dinv, __half* __restrict__ G, int N, int ntile) {
    __shared__ float Ws[EMB * EMB];      // 16 KB
    __shared__ float As[64 * AKP];       // 17.4 KB
    int t = threadIdx.x;

    for (int i = t * 4; i < EMB * EMB; i += 1024)
        *(float4*)(Ws + i) = *(const float4*)(W + i);

    int tc = t & 15;
    int tr = t >> 4;
    int j0 = tc * 4;

    for (int tile = blockIdx.x; tile < ntile; tile += gridDim.x) {
        int r0blk = tile * 64;
        float acc[4][4] = {{0.f}};

        __syncthreads();   // prev tile's readers (and Ws stage) done
        // stage A chunk: 64 rows x 64 halves -> fp32. 512 half8-slots,
        // thread t does slots t and t+256. Coalesced 16B loads.
#pragma unroll
        for (int n = 0; n < 2; n++) {
            int idx = t + n * 256;
            int row = idx >> 3;          // 8 half8 per row
            int hg  = idx & 7;
            int r = r0blk + row;
            if (r >= N) r = N - 1;
            union { float4 f4; __half2 h2[4]; } u;
            u.f4 = *(const float4*)(Hh + (size_t)r * EMB + hg * 8);
            float* dst = As + row * AKP + hg * 8;
            float2 p0 = __half22float2(u.h2[0]);
            float2 p1 = __half22float2(u.h2[1]);
            float2 p2 = __half22float2(u.h2[2]);
            float2 p3 = __half22float2(u.h2[3]);
            dst[0] = p0.x; dst[1] = p0.y; dst[2] = p1.x; dst[3] = p1.y;
            dst[4] = p2.x; dst[5] = p2.y; dst[6] = p3.x; dst[7] = p3.y;
        }
        __syncthreads();

#pragma unroll 2
        for (int k = 0; k < 64; k += 4) {
            float4 a[4];
#pragma unroll
            for (int i = 0; i < 4; i++)
                a[i] = *(const float4*)(As + (tr * 4 + i) * AKP + k);
#pragma unroll
            for (int kk = 0; kk < 4; kk++) {
                float4 wv = *(const float4*)(Ws + (k + kk) * EMB + j0);
#pragma unroll
                for (int i = 0; i < 4; i++) {
                    float av = (kk == 0) ? a[i].x : (kk == 1) ? a[i].y
                             : (kk == 2) ? a[i].z : a[i].w;
                    acc[i][0] = fmaf(av, wv.x, acc[i][0]);
                    acc[i][1] = fmaf(av, wv.y, acc[i][1]);
                    acc[i][2] = fmaf(av, wv.z, acc[i][2]);
                    acc[i][3] = fmaf(av, wv.w, acc[i][3]);
                }
            }
        }

        int r0 = r0blk + tr * 4;
#pragma unroll
        for (int i = 0; i < 4; i++) {
            if (r0 + i < N) {
                float s = dinv[r0 + i];
                union { __half2 h2[2]; float2 f2; } o;
                o.h2[0] = __floats2half2_rn(acc[i][0] * s, acc[i][1] * s);
                o.h2[1] = __floats2half2_rn(acc[i][2] * s, acc[i][3] * s);
                *(float2*)(G + (size_t)(r0 + i) * EMB + j0) = o.f2;
            }
        }
    }
}

// ---------------- Aggregation core (R12, proven) ----------------
// 8 lanes per 128B fp16 row (dwordx4); 8 groups/wave -> one load instr =
// 8 rows; 4 chains -> 32 rows outstanding. fp32 accumulate; epilogue
// shfl_xor(8,16,32).

__device__ __forceinline__ void h8_acc(float (&a)[8], float4 raw) {
    union { float4 f4; __half2 h2[4]; } u;
    u.f4 = raw;
    float2 p0 = __half22float2(u.h2[0]);
    float2 p1 = __half22float2(u.h2[1]);
    float2 p2 = __half22float2(u.h2[2]);
    float2 p3 = __half22float2(u.h2[3]);
    a[0] += p0.x; a[1] += p0.y; a[2] += p1.x; a[3] += p1.y;
    a[4] += p2.x; a[5] += p2.y; a[6] += p3.x; a[7] += p3.y;
}

__device__ __forceinline__ void agg_node8(const __half* __restrict__ G,
                                          const int* __restrict__ coff,
                                          int s, int e, int selfoff,
                                          int grp, int f8, float (&r)[8]) {
    const char* Gb = (const char*)G + f8 * 16;   // lane's 16B slice in a row
    float a0[8] = {0.f, 0.f, 0.f, 0.f, 0.f, 0.f, 0.f, 0.f};
    float a1[8] = {0.f, 0.f, 0.f, 0.f, 0.f, 0.f, 0.f, 0.f};
    float a2[8] = {0.f, 0.f, 0.f, 0.f, 0.f, 0.f, 0.f, 0.f};
    float a3[8] = {0.f, 0.f, 0.f, 0.f, 0.f, 0.f, 0.f, 0.f};
    if (grp == 0) h8_acc(a0, *(const float4*)(Gb + selfoff));  // self loop

    int i = s;
    if (i + 32 <= e) {
        int c0 = coff[i + grp];
        int c1 = coff[i + 8 + grp];
        int c2 = coff[i + 16 + grp];
        int c3 = coff[i + 24 + grp];
        while (true) {
            float4 g0 = *(const float4*)(Gb + (size_t)(unsigned)c0);
            float4 g1 = *(const float4*)(Gb + (size_t)(unsigned)c1);
            float4 g2 = *(const float4*)(Gb + (size_t)(unsigned)c2);
            float4 g3 = *(const float4*)(Gb + (size_t)(unsigned)c3);
            i += 32;
            bool more = (i + 32 <= e);
            if (more) {                       // prefetch next iter's offsets
                c0 = coff[i + grp];
                c1 = coff[i + 8 + grp];
                c2 = coff[i + 16 + grp];
                c3 = coff[i + 24 + grp];
            }
            h8_acc(a0, g0);
            h8_acc(a1, g1);
            h8_acc(a2, g2);
            h8_acc(a3, g3);
            if (!more) break;
        }
    }
    for (; i + 8 <= e; i += 8) {
        float4 g = *(const float4*)(Gb + (size_t)(unsigned)coff[i + grp]);
        h8_acc(a1, g);
    }
    if (grp < e - i) {
        float4 g = *(const float4*)(Gb + (size_t)(unsigned)coff[i + grp]);
        h8_acc(a2, g);
    }

#pragma unroll
    for (int k = 0; k < 8; k++) {
        float v = (a0[k] + a1[k]) + (a2[k] + a3[k]);
        v += __shfl_xor(v, 8, 64);
        v += __shfl_xor(v, 16, 64);
        v += __shfl_xor(v, 32, 64);
        r[k] = v;   // all 64 lanes: full sum for features [8*f8 .. 8*f8+7]
    }
}

// Aggregation writing fp16 h (inner layers): Hout row = 64 halves = 128B.
__global__ __launch_bounds__(256) void agg_h_k(
    const __half* __restrict__ G, const float* __restrict__ dinv,
    const int* __restrict__ rowptr, const int* __restrict__ coff,
    const float* __restrict__ bias, __half* __restrict__ Hout, int N) {
    int gw = (blockIdx.x * 256 + threadIdx.x) >> 6;
    int lane = threadIdx.x & 63;
    if (gw >= N) return;
    gw = __builtin_amdgcn_readfirstlane(gw);    // wave-uniform -> scalar loads
    int grp = lane >> 3;
    int f8 = lane & 7;
    int s = rowptr[gw], e = rowptr[gw + 1];
    float r[8];
    agg_node8(G, coff, s, e, gw << 7, grp, f8, r);
    if (grp == 0) {
        float d = dinv[gw];
        float4 b0v = *(const float4*)(bias + f8 * 8);
        float4 b1v = *(const float4*)(bias + f8 * 8 + 4);
        union { __half2 h2[4]; float4 f4; } o;
        o.h2[0] = __floats2half2_rn(r[0] * d + b0v.x, r[1] * d + b0v.y);
        o.h2[1] = __floats2half2_rn(r[2] * d + b0v.z, r[3] * d + b0v.w);
        o.h2[2] = __floats2half2_rn(r[4] * d + b1v.x, r[5] * d + b1v.y);
        o.h2[3] = __floats2half2_rn(r[6] * d + b1v.z, r[7] * d + b1v.w);
        *(float4*)((char*)Hout + ((size_t)gw << 7) + f8 * 16) = o.f4;
    }
}

// Final layer: fp32 y store + output projection (unchanged, proven).
__global__ __launch_bounds__(256) void agg_final_k(
    const __half* __restrict__ G, const float* __restrict__ dinv,
    const int* __restrict__ rowptr, const int* __restrict__ coff,
    const float* __restrict__ bias, const float* __restrict__ Wout,
    const float* __restrict__ bout, float* __restrict__ Y,
    float* __restrict__ Out, int N) {
    int gw = (blockIdx.x * 256 + threadIdx.x) >> 6;
    int lane = threadIdx.x & 63;
    if (gw >= N) return;
    gw = __builtin_amdgcn_readfirstlane(gw);
    int grp = lane >> 3;
    int f8 = lane & 7;
    int s = rowptr[gw], e = rowptr[gw + 1];
    float r[8];
    agg_node8(G, coff, s, e, gw << 7, grp, f8, r);
    float d = dinv[gw];
    float4 b0v = *(const float4*)(bias + f8 * 8);
    float4 b1v = *(const float4*)(bias + f8 * 8 + 4);
    float v0 = r[0] * d + b0v.x, v1 = r[1] * d + b0v.y;
    float v2 = r[2] * d + b0v.z, v3 = r[3] * d + b0v.w;
    float v4 = r[4] * d + b1v.x, v5 = r[5] * d + b1v.y;
    float v6 = r[6] * d + b1v.z, v7 = r[7] * d + b1v.w;
    if (grp == 0) {
        float* o = Y + (size_t)gw * EMB + f8 * 8;
        *(float4*)o = make_float4(v0, v1, v2, v3);
        *(float4*)(o + 4) = make_float4(v4, v5, v6, v7);
    }
    float4 w0v = *(const float4*)(Wout + f8 * 8);
    float4 w1v = *(const float4*)(Wout + f8 * 8 + 4);
    float p = v0 * w0v.x + v1 * w0v.y + v2 * w0v.z + v3 * w0v.w +
              v4 * w1v.x + v5 * w1v.y + v6 * w1v.z + v7 * w1v.w;
    p += __shfl_xor(p, 1, 8);
    p += __shfl_xor(p, 2, 8);
    p += __shfl_xor(p, 4, 8);
    if (lane == 0) Out[gw] = p + bout[0];
}

// ---------------- launch ----------------

extern "C" void kernel_launch(void* const* d_in, const int* in_sizes, int n_in,
                              void* d_out, int out_size, void* d_ws, size_t ws_size,
                              hipStream_t stream) {
    const float* x    = (const float*)d_in[0];
    const int*   ei   = (const int*)d_in[1];
    const float* W0   = (const float*)d_in[3];
    const float* b0   = (const float*)d_in[4];
    const float* W1   = (const float*)d_in[5];
    const float* b1   = (const float*)d_in[6];
    const float* W2   = (const float*)d_in[7];
    const float* b2   = (const float*)d_in[8];
    const float* W3   = (const float*)d_in[9];
    const float* b3   = (const float*)d_in[10];
    const float* Wout = (const float*)d_in[11];
    const float* bout = (const float*)d_in[12];

    const int N = in_sizes[0] / FEAT;      // 100000
    const int E = in_sizes[1] / 2;         // 3200000
    const int* srcp = ei;                  // edge_index[0]
    const int* dstp = ei + E;              // edge_index[1]
    const int nbin = (N + BINSIZE - 1) / BINSIZE;   // 391

    // workspace layout (regions padded to 64 elems for float4 alignment)
    const int NP = ((N + 64) + 63) / 64 * 64;   // holds N+1
    float* dinv  = (float*)d_ws;
    int* rowptr  = (int*)(dinv + NP);
    int* bincnt  = rowptr + NP;
    int* binptr  = bincnt + 1024;
    int* bincur  = binptr + 1024;
    int* col     = bincur + 1024;
    float* bufA  = (float*)(col + ((E + 63) / 64) * 64);
    int* ebuf    = (int*)bufA;             // aliased: ebuf dead before gemm0
    __half* Gbuf = (__half*)bufA;          // fp16 G (12.8MB), aliases ebuf
    __half* Yh   = Gbuf + (size_t)N * EMB; // fp16 inner h (12.8MB)

    float* Out = (float*)d_out;
    float* Y   = Out + N;                  // fp32 y output region (final only)

    const int ntile = (N + 63) / 64;               // 1563
    const int gemm_grid = (ntile < 768) ? ntile : 768;
    const int agg_blocks = (N + 3) / 4;            // 25000 exact-grid (R15:
                                                   // fine blocks win)
    const int nchunk = (E + CHUNK - 1) / CHUNK;

    // --- CSR build ---
    hipMemsetAsync(bincnt, 0, 1024 * sizeof(int), stream);
    bin_count_k<<<nchunk, 256, 0, stream>>>(dstp, bincnt, E);
    binscan_k<<<1, 512, 0, stream>>>(bincnt, binptr, bincur, nbin, E);
    bin_edges_k<<<nchunk, 256, 0, stream>>>(srcp, dstp, bincur, ebuf, E);
    build_csr_k<<<nbin, 256, 0, stream>>>(ebuf, binptr, rowptr, dinv, col, N, E, nbin);

    // --- layer 0 (K=128, fp32 x input) ---
    gemm_scale_k<FEAT><<<gemm_grid, 256, 0, stream>>>(x, W0, dinv, Gbuf, N, ntile);
    agg_h_k<<<agg_blocks, 256, 0, stream>>>(Gbuf, dinv, rowptr, col, b0, Yh, N);
    // --- layer 1 ---
    gemm_scale_h_k<<<gemm_grid, 256, 0, stream>>>(Yh, W1, dinv, Gbuf, N, ntile);
    agg_h_k<<<agg_blocks, 256, 0, stream>>>(Gbuf, dinv, rowptr, col, b1, Yh, N);
    // --- layer 2 ---
    gemm_scale_h_k<<<gemm_grid, 256, 0, stream>>>(Yh, W2, dinv, Gbuf, N, ntile);
    agg_h_k<<<agg_blocks, 256, 0, stream>>>(Gbuf, dinv, rowptr, col, b2, Yh, N);
    // --- layer 3 + output projection ---
    gemm_scale_h_k<<<gemm_grid, 256, 0, stream>>>(Yh, W3, dinv, Gbuf, N, ntile);
    agg_final_k<<<agg_blocks, 256, 0, stream>>>(Gbuf, dinv, rowptr, col, b3, Wout, bout,
                                                Y, Out, N);
}